// Round 1
// 2323.839 us; speedup vs baseline: 7.6288x; 7.6288x over previous
//
#include <hip/hip_runtime.h>
#include <hip/hip_bf16.h>
#include <stdint.h>

#define BATCH 128
#define TLEN  512
#define NHID  1024
#define NIN   128
#define NOUT  128

#define BT 16                       // batches per group
#define NT 128                      // hidden rows per block (8 waves x 16)
#define NGROUPS (BATCH / BT)        // 8
#define BLK_PER_G (NHID / NT)       // 8  -> barrier fan-in 8 (was 32)
#define GRID1 (NGROUPS * BLK_PER_G) // 64
#define NTHR1 512

#define KTOT (NHID + NIN)           // 1152 (tanh(h) ++ x_t along K)
#define NKB  (KTOT / 32)            // 36 MFMA k-blocks
#define AROW 1160                   // 1152 + 8 pad: stride 580 dw === 4 (mod 32)

typedef __attribute__((ext_vector_type(8))) short short8;
typedef __attribute__((ext_vector_type(4))) float floatx4;
typedef __attribute__((ext_vector_type(4))) unsigned short ushortx4;

__device__ __forceinline__ unsigned short f2bf(float f) {
  __hip_bfloat16 h = __float2bfloat16(f);
  return __builtin_bit_cast(unsigned short, h);
}

__device__ __forceinline__ float fast_tanh(float x) {
  float e = __expf(2.0f * x);
  return 1.0f - 2.0f / (e + 1.0f);
}

// ---------------------------------------------------------------------------
// Persistent scan kernel. 64 blocks x 512 threads, all co-resident.
// Block = (group g = blockIdx/8 -> batches g*16..+15, slice s = blockIdx%8 ->
// hidden rows s*128..+127; wave w owns a 16-row n-tile, W-slice in VGPRs).
//
// Coherence scheme (NO cache-wide fences):
//  - xbuf publish:  relaxed agent-scope atomic stores  (write-through sc0/sc1)
//  - xbuf consume:  relaxed agent-scope atomic 8B loads (bypass stale L1/L2)
//  - counters:      RELAXED agent atomicAdd / loads. Ordering comes from the
//    compiler-emitted s_waitcnt vmcnt(0) before each s_barrier: publish ->
//    __syncthreads() -> add guarantees data is at the coherence point first.
// This removes the per-step buffer_wbl2 / buffer_inv (full L2 writeback +
// invalidate) that the previous ACQUIRE/RELEASE fences generated.
// ---------------------------------------------------------------------------
__global__ __launch_bounds__(NTHR1) void rnn_scan(
    const float* __restrict__ x, const float* __restrict__ h0,
    const float* __restrict__ noise,
    const float* __restrict__ w_in_w, const float* __restrict__ w_in_b,
    const float* __restrict__ w_hh_w, const float* __restrict__ w_hh_b,
    float* __restrict__ out_hidden, float* __restrict__ out_final,
    unsigned short* __restrict__ xbuf, unsigned int* __restrict__ counters)
{
  __shared__ __align__(16) unsigned short Abuf[BT * AROW];  // 37,120 B

  const int tid  = threadIdx.x;
  const int wave = tid >> 6;
  const int lane = tid & 63;
  const int quad = lane >> 4;
  const int l16  = lane & 15;

  const int g  = blockIdx.x / BLK_PER_G;
  const int s  = blockIdx.x % BLK_PER_G;
  const int b0 = g * BT;
  const int n_g = s * NT + wave * 16 + l16;   // lane's hidden row (B-frag row, D col)

  unsigned int* cnt = counters + g * 64;      // 256-B separated counters
  unsigned short* xb0 = xbuf + (size_t)(g * 2 + 0) * BT * NHID;
  unsigned short* xb1 = xbuf + (size_t)(g * 2 + 1) * BT * NHID;

  // ---- stationary B fragments: B[k][n] = (k<1024 ? w_hh[n][k] : w_in[n][k-1024])
  short8 bfrag[NKB];
  {
    const float* whr = w_hh_w + (size_t)n_g * NHID;
    const float* wir = w_in_w + (size_t)n_g * NIN;
#pragma unroll
    for (int kb = 0; kb < NKB; ++kb) {
      int k0 = kb * 32 + quad * 8;
      const float* src = (kb < 32) ? (whr + k0) : (wir + (k0 - NHID));
      floatx4 a = *(const floatx4*)(src);
      floatx4 b = *(const floatx4*)(src + 4);
      short8 f;
      f[0] = (short)f2bf(a[0]); f[1] = (short)f2bf(a[1]);
      f[2] = (short)f2bf(a[2]); f[3] = (short)f2bf(a[3]);
      f[4] = (short)f2bf(b[0]); f[5] = (short)f2bf(b[1]);
      f[6] = (short)f2bf(b[2]); f[7] = (short)f2bf(b[3]);
      bfrag[kb] = f;
    }
  }

  const float bias_n = w_in_b[n_g] + w_hh_b[n_g];

  // h state in D-fragment layout: reg r <-> batch m = quad*4+r, col n = n_g
  float hs[4];
#pragma unroll
  for (int r = 0; r < 4; ++r)
    hs[r] = h0[(size_t)(b0 + quad * 4 + r) * NHID + n_g];

  // publish tanh(h0) (step-0 input), parity 0 — write-through atomic stores
#pragma unroll
  for (int r = 0; r < 4; ++r)
    __hip_atomic_store(&xb0[(quad * 4 + r) * NHID + n_g], f2bf(fast_tanh(hs[r])),
                       __ATOMIC_RELAXED, __HIP_MEMORY_SCOPE_AGENT);

  __syncthreads();  // drains vmcnt -> stores visible at coherence point
  if (tid == 0)
    __hip_atomic_fetch_add(cnt, 1u, __ATOMIC_RELAXED, __HIP_MEMORY_SCOPE_AGENT);

  for (int t = 0; t < TLEN; ++t) {
    // ---- prefetch noise (independent of the exchange; overlaps the spin)
    float nz[4];
#pragma unroll
    for (int r = 0; r < 4; ++r)
      nz[r] = noise[((size_t)t * BATCH + (b0 + quad * 4 + r)) * NHID + n_g];

    // ---- stage x tile 16x128 fp32 -> bf16 into K columns 1024..1151.
    // Legal before the spin: prev step's post-MFMA barrier already passed,
    // so no wave of this block still reads Abuf.
    {
      int xrow = tid >> 5;                 // 16 rows x 32 threads
      int c0 = (tid & 31) * 4;
      const float* xp = x + ((size_t)(b0 + xrow) * TLEN + t) * NIN + c0;
      floatx4 v = *(const floatx4*)(xp);
      ushortx4 p;
      p[0] = f2bf(v[0]); p[1] = f2bf(v[1]);
      p[2] = f2bf(v[2]); p[3] = f2bf(v[3]);
      *(ushortx4*)(&Abuf[xrow * AROW + NHID + c0]) = p;
    }

    // ---- wait until all 8 blocks of the group published step-t input
    if (tid == 0) {
      const unsigned int target = (unsigned int)(t + 1) * BLK_PER_G;
      while (__hip_atomic_load(cnt, __ATOMIC_RELAXED, __HIP_MEMORY_SCOPE_AGENT) < target)
        __builtin_amdgcn_s_sleep(1);
    }
    __syncthreads();

    const unsigned short* xsrc = (t & 1) ? xb1 : xb0;
    unsigned short*       xdst = (t & 1) ? xb0 : xb1;

    // ---- stage tanh tile 16x1024 bf16 (32 KB) via coherent 8B loads,
    // 8 outstanding per thread, then distribute to LDS.
    {
      unsigned long long* src8 = (unsigned long long*)xsrc;
      unsigned long long tmp[8];
#pragma unroll
      for (int it = 0; it < 8; ++it)
        tmp[it] = __hip_atomic_load(&src8[it * NTHR1 + tid],
                                    __ATOMIC_RELAXED, __HIP_MEMORY_SCOPE_AGENT);
#pragma unroll
      for (int it = 0; it < 8; ++it) {
        int u = it * NTHR1 + tid;          // 8-B units, 4096 total
        int row = u >> 8;                  // 256 units per 2048-B row
        int c8 = u & 255;
        *(unsigned long long*)(&Abuf[row * AROW + c8 * 4]) = tmp[it];
      }
    }

    __syncthreads();

    // ---- MFMA: D[16 batch x 16 n] += A[16 x 1152] * B[1152 x 16]
    floatx4 acc = {0.f, 0.f, 0.f, 0.f};
#pragma unroll
    for (int kb = 0; kb < NKB; ++kb) {
      short8 af = *(const short8*)(&Abuf[l16 * AROW + kb * 32 + quad * 8]);
      acc = __builtin_amdgcn_mfma_f32_16x16x32_bf16(af, bfrag[kb], acc, 0, 0, 0);
    }

    // ---- leaky update + noise, write hidden_list, publish tanh(h_new)
#pragma unroll
    for (int r = 0; r < 4; ++r) {
      int m = quad * 4 + r;
      float hn = 0.75f * hs[r] + 0.25f * (acc[r] + bias_n) + 0.025f * nz[r];
      hs[r] = hn;
      out_hidden[((size_t)(b0 + m) * TLEN + t) * NHID + n_g] = hn;
      if (t < TLEN - 1)
        __hip_atomic_store(&xdst[m * NHID + n_g], f2bf(fast_tanh(hn)),
                           __ATOMIC_RELAXED, __HIP_MEMORY_SCOPE_AGENT);
    }
    if (t < TLEN - 1) {
      __syncthreads();  // all waves' publish stores drained (pre-barrier vmcnt(0))
      if (tid == 0)
        __hip_atomic_fetch_add(cnt, 1u, __ATOMIC_RELAXED, __HIP_MEMORY_SCOPE_AGENT);
    }
  }

#pragma unroll
  for (int r = 0; r < 4; ++r)
    out_final[(size_t)(b0 + quad * 4 + r) * NHID + n_g] = hs[r];
}

// ---------------------------------------------------------------------------
// Output projection: out[r][o] = clip(hid[r][:] . w_out[o][:] + b[o], +-20)
// r = b*512+t (contiguous rows of out_hidden). M-tile 64/block, N=128, K=1024
// in 4 chunks of 256 staged to LDS as bf16.
// ---------------------------------------------------------------------------
#define NTHR2 256
#define M2 64
#define BK2 256
#define WROW2 264   // 256+8 pad (ushort): stride 132 dw === 4 (mod 32)
#define AROW2 260   // 256+4 pad (float):  stride 260 dw === 4 (mod 32)

__global__ __launch_bounds__(NTHR2) void rnn_outproj(
    const float* __restrict__ hid,      // [B*T, 1024]
    const float* __restrict__ w_out_w,  // [128, 1024]
    const float* __restrict__ w_out_b,  // [128]
    float* __restrict__ out)            // [B*T, 128]
{
  __shared__ unsigned short Wlds[NOUT * WROW2]; // 67,584 B
  __shared__ float Alds[M2 * AROW2];            // 66,560 B

  const int tid  = threadIdx.x;
  const int wave = tid >> 6;
  const int lane = tid & 63;
  const int quad = lane >> 4;
  const int l16  = lane & 15;
  const size_t row0 = (size_t)blockIdx.x * M2;

  floatx4 acc[8];
#pragma unroll
  for (int i = 0; i < 8; ++i) acc[i] = (floatx4){0.f, 0.f, 0.f, 0.f};

  for (int kc = 0; kc < 4; ++kc) {
    // stage W chunk: 128 x 256 fp32 -> bf16 (16 iters/thread, independent)
#pragma unroll
    for (int it = 0; it < 16; ++it) {
      int u = it * NTHR2 + tid;        // 8-float units, 4096 total
      int row = u >> 5;
      int c8 = u & 31;
      const float* src = w_out_w + (size_t)row * NHID + kc * BK2 + c8 * 8;
      floatx4 w0 = *(const floatx4*)(src);
      floatx4 w1 = *(const floatx4*)(src + 4);
      short8 p;
      p[0] = (short)f2bf(w0[0]); p[1] = (short)f2bf(w0[1]);
      p[2] = (short)f2bf(w0[2]); p[3] = (short)f2bf(w0[3]);
      p[4] = (short)f2bf(w1[0]); p[5] = (short)f2bf(w1[1]);
      p[6] = (short)f2bf(w1[2]); p[7] = (short)f2bf(w1[3]);
      *(short8*)(&Wlds[row * WROW2 + c8 * 8]) = p;
    }
    // stage A chunk: 64 x 256 fp32 (16 iters/thread)
#pragma unroll
    for (int it = 0; it < 16; ++it) {
      int u = it * NTHR2 + tid;        // float4 units, 4096 total
      int row = u >> 6;
      int c4 = u & 63;
      *(floatx4*)(&Alds[row * AROW2 + c4 * 4]) =
          *(const floatx4*)(hid + (row0 + row) * NHID + kc * BK2 + c4 * 4);
    }
    __syncthreads();

#pragma unroll
    for (int kb = 0; kb < 8; ++kb) {
      const float* ap = &Alds[(wave * 16 + l16) * AROW2 + kb * 32 + quad * 8];
      floatx4 a0 = *(const floatx4*)(ap);
      floatx4 a1 = *(const floatx4*)(ap + 4);
      short8 af;
      af[0] = (short)f2bf(a0[0]); af[1] = (short)f2bf(a0[1]);
      af[2] = (short)f2bf(a0[2]); af[3] = (short)f2bf(a0[3]);
      af[4] = (short)f2bf(a1[0]); af[5] = (short)f2bf(a1[1]);
      af[6] = (short)f2bf(a1[2]); af[7] = (short)f2bf(a1[3]);
#pragma unroll
      for (int nt = 0; nt < 8; ++nt) {
        short8 bf = *(const short8*)(&Wlds[(nt * 16 + l16) * WROW2 + kb * 32 + quad * 8]);
        acc[nt] = __builtin_amdgcn_mfma_f32_16x16x32_bf16(af, bf, acc[nt], 0, 0, 0);
      }
    }
    __syncthreads();
  }

#pragma unroll
  for (int nt = 0; nt < 8; ++nt) {
    int n = nt * 16 + l16;
    float bias = w_out_b[n];
#pragma unroll
    for (int r = 0; r < 4; ++r) {
      size_t m = row0 + wave * 16 + quad * 4 + r;
      float v = acc[nt][r] + bias;
      v = fminf(fmaxf(v, -20.f), 20.f);
      out[m * NOUT + n] = v;
    }
  }
}

extern "C" void kernel_launch(void* const* d_in, const int* in_sizes, int n_in,
                              void* d_out, int out_size, void* d_ws, size_t ws_size,
                              hipStream_t stream) {
  const float* x       = (const float*)d_in[0];
  const float* h0      = (const float*)d_in[1];
  const float* noise   = (const float*)d_in[2];
  const float* w_in_w  = (const float*)d_in[3];
  const float* w_in_b  = (const float*)d_in[4];
  const float* w_hh_w  = (const float*)d_in[5];
  const float* w_hh_b  = (const float*)d_in[6];
  const float* w_out_w = (const float*)d_in[7];
  const float* w_out_b = (const float*)d_in[8];
  // d_in[9] = length (== 512), compile-time constant here

  float* out_hidden = (float*)d_out;                                  // [128,512,1024]
  float* out_list   = out_hidden + (size_t)BATCH * TLEN * NHID;       // [128,512,128]
  float* out_final  = out_list + (size_t)BATCH * TLEN * NOUT;         // [128,1024]

  unsigned int*   counters = (unsigned int*)d_ws;                     // first 4 KB
  unsigned short* xbuf     = (unsigned short*)((char*)d_ws + 4096);   // 512 KB

  hipMemsetAsync(d_ws, 0, 4096, stream);  // zero barrier counters (graph-safe)

  hipLaunchKernelGGL(rnn_scan, dim3(GRID1), dim3(NTHR1), 0, stream,
                     x, h0, noise, w_in_w, w_in_b, w_hh_w, w_hh_b,
                     out_hidden, out_final, xbuf, counters);

  hipLaunchKernelGGL(rnn_outproj, dim3((BATCH * TLEN) / M2), dim3(NTHR2), 0, stream,
                     out_hidden, w_out_w, w_out_b, out_list);
}